// Round 1
// baseline (370.595 us; speedup 1.0000x reference)
//
#include <hip/hip_runtime.h>
#include <cstdint>
#include <cstddef>

// Problem constants (fixed by reference setup_inputs)
#define BATCH 8
#define CH    128
#define NPTS  65536
#define NOBJ  64
#define SEGEL (CH * NOBJ)   // 8192 accumulator elements

// Monotonic order-preserving encode: larger float -> larger uint.
// Encoded 0 only arises from -NaN, so 0 is a safe empty sentinel.
__device__ __forceinline__ uint32_t enc_f32(float f) {
    uint32_t x = __float_as_uint(f);
    return x ^ ((uint32_t)((int32_t)x >> 31) | 0x80000000u);
}
__device__ __forceinline__ float dec_f32(uint32_t u) {
    uint32_t x = u ^ ((uint32_t)((int32_t)(~u) >> 31) | 0x80000000u);
    return __uint_as_float(x);
}

// ---------------------------------------------------------------------------
// seg_max_ws: LDS-privatized segment max, depth-2 software pipeline.
// Lane map: cl = lane>>3 (8 channels per instr), pq = lane&7.
// Depth-2 ping-pong: loads for channel-block cb+16 are issued AFTER the
// atomics that consume cb, so the vmcnt wait age for any buffer is a full
// iteration (~>900 cyc) -> HBM latency fully hidden under LDS-atomic work.
// Swizzle: acc[c][s ^ (c&7)]; since cb % 8 == 0, (cb+cl)&7 == cl, so the
// per-thread swizzled seg ids are loop-invariant.
// ---------------------------------------------------------------------------
template <int NCHUNK, int TPB>
__global__ __launch_bounds__(TPB, 4) void seg_max_ws(
        const float* __restrict__ pf,     // (B, C, N)
        const int*   __restrict__ bidx,   // (B, N)
        uint32_t*    __restrict__ ws)     // (B*NCHUNK, SEGEL) encoded partials
{
    constexpr int PPB = NPTS / NCHUNK;        // points per block
    constexpr int QPP = TPB / 8;              // quads covered per pass
    constexpr int J   = PPB / (QPP * 4);      // load passes
    static_assert(J >= 1 && PPB % (QPP * 4) == 0, "bad geometry");

    __shared__ uint32_t acc[SEGEL];           // 32 KiB

    const int tid  = threadIdx.x;
    const int wave = tid >> 6;
    const int lane = tid & 63;
    const int cl   = lane >> 3;               // channel-local 0..7
    const int pq   = lane & 7;                // quad-local 0..7

    const int b     = blockIdx.x / NCHUNK;
    const int chunk = blockIdx.x % NCHUNK;
    const int n0    = chunk * PPB;

    // zero acc (vector LDS writes)
    for (int i = tid; i < SEGEL / 4; i += TPB)
        ((uint4*)acc)[i] = make_uint4(0u, 0u, 0u, 0u);

    // Pre-swizzled segment ids for this thread's J*4 points.
    int s[J][4];
    #pragma unroll
    for (int j = 0; j < J; ++j) {
        const int q = j * QPP + wave * 8 + pq;
        const int4 sv = *(const int4*)(bidx + (size_t)b * NPTS + n0 + q * 4);
        s[j][0] = sv.x ^ cl;  s[j][1] = sv.y ^ cl;
        s[j][2] = sv.z ^ cl;  s[j][3] = sv.w ^ cl;
    }
    __syncthreads();

    const float* pbase = pf + (size_t)b * CH * NPTS + n0;
    const int qoff = (wave * 8 + pq) * 4;

    // depth-2 ping-pong prefetch buffers (statically renamed under unroll)
    float4 buf[2][J];
    #pragma unroll
    for (int j = 0; j < J; ++j)
        buf[0][j] = *(const float4*)(pbase + (size_t)cl * NPTS + j * (QPP * 4) + qoff);
    #pragma unroll
    for (int j = 0; j < J; ++j)
        buf[1][j] = *(const float4*)(pbase + (size_t)(8 + cl) * NPTS + j * (QPP * 4) + qoff);

    #pragma unroll
    for (int ci = 0; ci < CH / 8; ++ci) {
        const int cb = ci * 8;
        uint32_t* row = acc + (cb + cl) * NOBJ;
        float4* cur = buf[ci & 1];
        #pragma unroll
        for (int j = 0; j < J; ++j) {
            atomicMax(&row[s[j][0]], enc_f32(cur[j].x));
            atomicMax(&row[s[j][1]], enc_f32(cur[j].y));
            atomicMax(&row[s[j][2]], enc_f32(cur[j].z));
            atomicMax(&row[s[j][3]], enc_f32(cur[j].w));
        }
        // refill the slot just consumed with channel-block cb+16
        if (ci + 2 < CH / 8) {
            const float* pn = pbase + (size_t)(cb + 16 + cl) * NPTS;
            #pragma unroll
            for (int j = 0; j < J; ++j)
                cur[j] = *(const float4*)(pn + j * (QPP * 4) + qoff);
        }
    }
    __syncthreads();

    // Coalesced non-atomic partial dump (16B stores).
    uint4* wsb = (uint4*)(ws + (size_t)blockIdx.x * SEGEL);
    for (int e = tid; e < SEGEL / 4; e += TPB) wsb[e] = ((const uint4*)acc)[e];
}

// Max over per-chunk partials + decode + finite guard. dwordx4 loads,
// 256 blocks x 64 threads so all CUs contribute load bandwidth; unroll-16
// keeps ~4 MB in flight.
template <int NCHUNK>
__global__ __launch_bounds__(64) void reduce_ws(
        const uint32_t* __restrict__ ws, float* __restrict__ out)
{
    const int g  = blockIdx.x * 64 + threadIdx.x;   // 0 .. B*SEGEL/4-1
    const int b  = g >> 11;                         // SEGEL/4 = 2048
    const int e4 = (g & 2047) * 4;
    const uint4* p = (const uint4*)(ws + (size_t)b * NCHUNK * SEGEL + e4);
    uint4 m = make_uint4(0u, 0u, 0u, 0u);
    #pragma unroll 16
    for (int k = 0; k < NCHUNK; ++k) {
        const uint4 v = p[(size_t)k * (SEGEL / 4)];
        m.x = max(m.x, v.x); m.y = max(m.y, v.y);
        m.z = max(m.z, v.z); m.w = max(m.w, v.w);
    }
    const int c   = e4 >> 6;
    const int sw0 = e4 & 63;
    const uint32_t mv[4] = {m.x, m.y, m.z, m.w};
    #pragma unroll
    for (int i = 0; i < 4; ++i) {
        const int seg = (sw0 + i) ^ (c & 7);        // un-swizzle
        float f = 0.0f;
        if (mv[i]) { f = dec_f32(mv[i]); if (!isfinite(f)) f = 0.0f; }
        out[(size_t)(b * NOBJ + seg) * CH + c] = f;
    }
}

// ---------------------------------------------------------------------------
// Fallback path (ws too small): global-atomic merge.
// ---------------------------------------------------------------------------
__global__ __launch_bounds__(256) void init_out_kernel(uint32_t* __restrict__ out, int n) {
    int i = blockIdx.x * blockDim.x + threadIdx.x;
    if (i < n) out[i] = 0u;
}

__global__ __launch_bounds__(256) void seg_max_atomic(
        const float* __restrict__ pf, const int* __restrict__ bidx,
        uint32_t* __restrict__ out)
{
    constexpr int PPB = 1024;
    __shared__ uint32_t acc[SEGEL];
    const int tid   = threadIdx.x;
    const int b     = blockIdx.x / (NPTS / PPB);
    const int chunk = blockIdx.x % (NPTS / PPB);
    const int n0    = chunk * PPB;
    for (int i = tid; i < SEGEL; i += 256) acc[i] = 0u;
    __syncthreads();
    const int4 sv = *(const int4*)(bidx + (size_t)b * NPTS + n0 + tid * 4);
    const float* p = pf + (size_t)b * CH * NPTS + n0 + tid * 4;
    uint32_t* row = acc;
    #pragma unroll 4
    for (int c = 0; c < CH; ++c, p += NPTS, row += NOBJ) {
        const float4 v = *(const float4*)p;
        atomicMax(&row[sv.x], enc_f32(v.x));
        atomicMax(&row[sv.y], enc_f32(v.y));
        atomicMax(&row[sv.z], enc_f32(v.z));
        atomicMax(&row[sv.w], enc_f32(v.w));
    }
    __syncthreads();
    for (int e = tid; e < SEGEL; e += 256) {
        const int seg = e & (NOBJ - 1);
        const int c   = e >> 6;
        const uint32_t v = acc[c * NOBJ + seg];
        if (v) atomicMax(&out[(size_t)(b * NOBJ + seg) * CH + c], v);
    }
}

__global__ __launch_bounds__(256) void finalize_kernel(uint32_t* __restrict__ out, int n) {
    int i = blockIdx.x * blockDim.x + threadIdx.x;
    if (i >= n) return;
    const uint32_t u = out[i];
    float f = 0.0f;
    if (u) { f = dec_f32(u); if (!isfinite(f)) f = 0.0f; }
    ((float*)out)[i] = f;
}

extern "C" void kernel_launch(void* const* d_in, const int* in_sizes, int n_in,
                              void* d_out, int out_size, void* d_ws, size_t ws_size,
                              hipStream_t stream) {
    const float* pf   = (const float*)d_in[0];
    const int*   bidx = (const int*)d_in[1];

    const size_t need64 = (size_t)BATCH * 64 * SEGEL * 4;   // 16 MiB

    if (ws_size >= need64) {
        uint32_t* ws = (uint32_t*)d_ws;
        seg_max_ws<64, 512><<<BATCH * 64, 512, 0, stream>>>(pf, bidx, ws);
        reduce_ws<64><<<256, 64, 0, stream>>>(ws, (float*)d_out);
    } else {
        uint32_t* out = (uint32_t*)d_out;
        init_out_kernel<<<(out_size + 255) / 256, 256, 0, stream>>>(out, out_size);
        seg_max_atomic<<<BATCH * (NPTS / 1024), 256, 0, stream>>>(pf, bidx, out);
        finalize_kernel<<<(out_size + 255) / 256, 256, 0, stream>>>(out, out_size);
    }
}